// Round 9
// baseline (56.858 us; speedup 1.0000x reference)
//
#include <hip/hip_runtime.h>
#include <math.h>

#define Bq 2
#define Tq 96
#define Nq 64
#define CIN 16
#define COUT 32
#define PATCH 24
#define NPq 4
#define JC 4
#define ATT_SIZE (Bq * Nq * Nq * Tq * COUT)   // 25165824
#define HP_SIZE (Bq * Nq * Tq * COUT)         // 393216
#define H_ROWS (Bq * NPq * Nq * PATCH)        // 12288
#define SLAB (Nq * PATCH * COUT)              // 49152 floats per (b,s)

typedef float f4 __attribute__((ext_vector_type(4)));

// ---------------------------------------------------------------------------
// Kernel 1: h = x_flat(12288,16) @ W(16,32).
// ---------------------------------------------------------------------------
__global__ __launch_bounds__(256) void h_gemm_kernel(
    const float* __restrict__ x, const float* __restrict__ W,
    float* __restrict__ h) {
    __shared__ float Wl[CIN * COUT];
    __shared__ float xs[8 * CIN];
    int tid = threadIdx.x;
    Wl[tid]       = W[tid];
    Wl[tid + 256] = W[tid + 256];
    if (tid < 8 * CIN) xs[tid] = x[blockIdx.x * (8 * CIN) + tid];
    __syncthreads();
    int rl = tid >> 5;
    int c  = tid & 31;
    float acc = 0.f;
#pragma unroll
    for (int k = 0; k < CIN; ++k)
        acc += xs[rl * CIN + k] * Wl[k * COUT + c];
    h[blockIdx.x * 256 + tid] = acc;
}

// ---------------------------------------------------------------------------
// Kernel 2: block = (b, i, jc); 192 threads = 2 jsub x 96 t-slots. Each
// thread owns ALL 32 channels of one t (8 x f4 registers) for 8 j's:
// softmax is fully in-thread (7 f4-adds + 3 scalar adds + rcp) — ZERO
// cross-lane ops, zero LDS traffic in the hot loop. Per j the thread
// stores 128 B contiguous (8 dwordx4 burst). Cross-jsub partial-sum via
// one LDS pass; cross-jc via part slabs + kernel 3.
// ---------------------------------------------------------------------------
__global__ __launch_bounds__(192) void att_kernel(
    const float* __restrict__ h, const float* __restrict__ adj,
    float* __restrict__ att, float* __restrict__ part) {
    const int bi = blockIdx.x;
    const int jc = bi & 3;
    const int i  = (bi >> 2) & 63;
    const int b  = bi >> 8;
    const int tid  = threadIdx.x;
    const int t    = tid % 96;
    const int jsub = tid / 96;        // 0..1
    const int s = t & 3;
    const int p = t >> 2;
    const int j0 = jc * 16 + jsub * 8;

    __shared__ float adjrow[16];
    __shared__ float red[96 * 32];    // 12 KB
    if (tid < 16) adjrow[tid] = adj[i * Nq + jc * 16 + tid];
    __syncthreads();

    const float* hb = h + (size_t)(b * NPq + s) * SLAB;
    f4 hi[8], acc[8];
#pragma unroll
    for (int q = 0; q < 8; ++q) {
        hi[q]  = *(const f4*)(hb + (i * PATCH + p) * COUT + q * 4);
        acc[q] = (f4){0.f, 0.f, 0.f, 0.f};
    }

    // att flat index: (((b*N+i)*N+j)*T + t)*COUT
    size_t outbase = ((size_t)((b * Nq + i) * Nq + j0) * Tq + t) * COUT;
    const size_t jstride = (size_t)Tq * COUT;   // 3072

#pragma unroll
    for (int jj = 0; jj < 8; ++jj) {
        const float aj = adjrow[jsub * 8 + jj];
        const float* hjp = hb + ((j0 + jj) * PATCH + p) * COUT;

        f4 ex[8];
#pragma unroll
        for (int q = 0; q < 8; ++q) {
            f4 e = hi[q] * (*(const f4*)(hjp + q * 4));
            e.x = fmaxf(e.x, 0.2f * e.x) * aj;   // LeakyReLU(0.2) * adj
            e.y = fmaxf(e.y, 0.2f * e.y) * aj;
            e.z = fmaxf(e.z, 0.2f * e.z) * aj;
            e.w = fmaxf(e.w, 0.2f * e.w) * aj;
            ex[q].x = __expf(e.x); ex[q].y = __expf(e.y);
            ex[q].z = __expf(e.z); ex[q].w = __expf(e.w);
        }
        // in-thread sum over 32 channels
        f4 s0 = (ex[0] + ex[1]) + (ex[2] + ex[3]);
        f4 s1 = (ex[4] + ex[5]) + (ex[6] + ex[7]);
        f4 sv = s0 + s1;
        const float sm = (sv.x + sv.y) + (sv.z + sv.w);
        const float inv = __builtin_amdgcn_rcpf(sm);

        float* op = att + outbase + (size_t)jj * jstride;
#pragma unroll
        for (int q = 0; q < 8; ++q) {
            f4 a = ex[q] * inv;
            acc[q] += a;
            *(f4*)(op + q * 4) = a;
        }
    }

    // cross-jsub reduction, then partial to part[jc] in output layout [b,i,t,c]
    if (jsub == 1) {
#pragma unroll
        for (int q = 0; q < 8; ++q)
            *(f4*)(&red[t * COUT + q * 4]) = acc[q];
    }
    __syncthreads();
    if (jsub == 0) {
        float* pp = part + (size_t)jc * HP_SIZE
                         + ((size_t)((b * Nq + i) * Tq + t)) * COUT;
#pragma unroll
        for (int q = 0; q < 8; ++q) {
            f4 r = *(const f4*)(&red[t * COUT + q * 4]);
            *(f4*)(pp + q * 4) = acc[q] + r;
        }
    }
}

// ---------------------------------------------------------------------------
// Kernel 3: h_prime = elu( (sum of 4 partials) * h_flat ), float4 per thread.
// ---------------------------------------------------------------------------
__global__ __launch_bounds__(256) void hprime_kernel(
    const float* __restrict__ part, const float* __restrict__ h,
    float* __restrict__ hprime) {
    const int vid  = blockIdx.x * 256 + threadIdx.x;
    const int base = vid * 4;
    const int c  = base & 31;
    const int t  = (base >> 5) % Tq;
    const int bi = base / (COUT * Tq);
    const int i  = bi & 63;
    const int b  = bi >> 6;

    f4 a0 = *(const f4*)(part + base);
    f4 a1 = *(const f4*)(part + base + HP_SIZE);
    f4 a2 = *(const f4*)(part + base + 2 * HP_SIZE);
    f4 a3 = *(const f4*)(part + base + 3 * HP_SIZE);
    f4 asum = (a0 + a1) + (a2 + a3);

    const int s2 = t / PATCH;
    const int p2 = t % PATCH;
    const f4 hv = *(const f4*)(h + (size_t)((b * NPq + s2) * Nq + i) * (PATCH * COUT)
                                 + p2 * COUT + c);
    f4 v = asum * hv;
    v.x = v.x >= 0.f ? v.x : expm1f(v.x);
    v.y = v.y >= 0.f ? v.y : expm1f(v.y);
    v.z = v.z >= 0.f ? v.z : expm1f(v.z);
    v.w = v.w >= 0.f ? v.w : expm1f(v.w);
    *(f4*)(hprime + base) = v;
}

extern "C" void kernel_launch(void* const* d_in, const int* in_sizes, int n_in,
                              void* d_out, int out_size, void* d_ws, size_t ws_size,
                              hipStream_t stream) {
    (void)in_sizes; (void)n_in; (void)out_size; (void)ws_size;
    const float* x   = (const float*)d_in[0];
    const float* adj = (const float*)d_in[1];
    const float* W   = (const float*)d_in[2];

    float* h    = (float*)d_ws;                    // 393216 floats
    float* part = (float*)d_ws + H_ROWS * COUT;    // 4 * 393216 floats
    float* att  = (float*)d_out;
    float* hp   = (float*)d_out + ATT_SIZE;

    hipLaunchKernelGGL(h_gemm_kernel, dim3(H_ROWS / 8), dim3(256), 0, stream,
                       x, W, h);
    // (b, i, jc) = 2*64*4 = 512 blocks
    hipLaunchKernelGGL(att_kernel, dim3(Bq * Nq * JC), dim3(192), 0, stream,
                       h, adj, att, part);
    hipLaunchKernelGGL(hprime_kernel, dim3(HP_SIZE / 4 / 256), dim3(256), 0, stream,
                       part, h, hp);
}

// Round 10
// 44.121 us; speedup vs baseline: 1.2887x; 1.2887x over previous
//
#include <hip/hip_runtime.h>
#include <math.h>

#define Bq 2
#define Tq 96
#define Nq 64
#define CIN 16
#define COUT 32
#define PATCH 24
#define NPq 4
#define ATT_SIZE (Bq * Nq * Nq * Tq * COUT)   // 25165824

typedef float f4 __attribute__((ext_vector_type(4)));

// ---------------------------------------------------------------------------
// Single fused kernel. Block = (b, s, i-pair): 256 blocks x 768 threads
// (1 block/CU, 12 waves). Threads: c4 = tid&7 (f4 channel quad), p =
// (tid>>3)%24, jsub = tid/192 (16 j's each). Each thread computes its h
// fragments directly from x with its W column-slice in registers (no h
// buffer, no separate GEMM kernel, no inter-kernel gap):
//   hi0/hi1 (own rows), hj[16] (shared across both i's), hf0/hf1 (epilogue).
// Main loop = round-6-proven shape: leaky*adj -> exp -> 3x shfl_xor(8-lane)
// softmax -> f4 store (lane-adjacent 16B => coalesced 128B lines).
// Sum_j partials cross jsub via LDS; h_prime = elu(sum*h_flat) fused.
// ---------------------------------------------------------------------------
__global__ __launch_bounds__(768, 3) void gat_fused_kernel(
    const float* __restrict__ x, const float* __restrict__ adj,
    const float* __restrict__ W,
    float* __restrict__ att, float* __restrict__ hprime) {
  const int bi = blockIdx.x;
  const int s  = bi & 3;
  const int ig = (bi >> 2) & 31;
  const int b  = bi >> 7;
  const int i0 = ig * 2;
  const int tid  = threadIdx.x;
  const int c4   = tid & 7;            // f4-quad index, c0 = c4*4
  const int p    = (tid >> 3) % PATCH; // 0..23
  const int jsub = tid / 192;          // 0..3
  const int j0   = jsub * 16;
  const int t    = p * NPq + s;

  __shared__ float adjr[2][Nq];
  __shared__ f4 red[2][4][PATCH][8];   // [i][jsub][p][c4] = 24 KB

  if (tid < 2 * Nq)
    adjr[tid >> 6][tid & 63] = adj[(i0 + (tid >> 6)) * Nq + (tid & 63)];
  __syncthreads();

  const f4* x4 = (const f4*)x;   // x row (16 f) = 4 f4
  const f4* W4 = (const f4*)W;   // W row k (32 f) = 8 f4

  // W column-slice: W[k][c0..c0+3] for k=0..15 (64 VGPR, dies before stores)
  f4 Wr[16];
#pragma unroll
  for (int k = 0; k < 16; ++k) Wr[k] = W4[k * 8 + c4];

  // row-dot: h[row][c0..c0+3] = sum_k x[row][k] * W[k][c0..c0+3]
  auto rowdot = [&](int row) -> f4 {
    const f4 x0 = x4[row * 4 + 0], x1 = x4[row * 4 + 1];
    const f4 x2 = x4[row * 4 + 2], x3 = x4[row * 4 + 3];
    f4 a = x0.x * Wr[0];
    a += x0.y * Wr[1];  a += x0.z * Wr[2];  a += x0.w * Wr[3];
    a += x1.x * Wr[4];  a += x1.y * Wr[5];  a += x1.z * Wr[6];  a += x1.w * Wr[7];
    a += x2.x * Wr[8];  a += x2.y * Wr[9];  a += x2.z * Wr[10]; a += x2.w * Wr[11];
    a += x3.x * Wr[12]; a += x3.y * Wr[13]; a += x3.z * Wr[14]; a += x3.w * Wr[15];
    return a;
  };

  const int rbase = (b * NPq + s) * Nq;        // + n  -> *PATCH + p
  const int s2 = t / PATCH, p2 = t % PATCH;    // h_flat row split

  const f4 hi0 = rowdot((rbase + i0) * PATCH + p);
  const f4 hi1 = rowdot((rbase + i0 + 1) * PATCH + p);
  const f4 hf0 = rowdot(((b * NPq + s2) * Nq + i0) * PATCH + p2);
  const f4 hf1 = rowdot(((b * NPq + s2) * Nq + i0 + 1) * PATCH + p2);

  f4 hj[16];
#pragma unroll
  for (int jj = 0; jj < 16; ++jj)
    hj[jj] = rowdot((rbase + j0 + jj) * PATCH + p);
  // Wr dead from here: main loop runs on hj/hi/acc only.

  f4 acc0 = {0.f, 0.f, 0.f, 0.f};
  f4 acc1 = {0.f, 0.f, 0.f, 0.f};
  const int c0 = c4 * 4;
  // att flat: (((b*N+i)*N+j)*T + t)*COUT + c
  size_t ob0 = ((size_t)((b * Nq + i0) * Nq + j0) * Tq + t) * COUT + c0;
  size_t ob1 = ob0 + (size_t)Nq * Tq * COUT;
  const size_t jstride = (size_t)Tq * COUT;   // 3072

#pragma unroll 4
  for (int jj = 0; jj < 16; ++jj) {
    const f4 hjv = hj[jj];
    const float a0 = adjr[0][j0 + jj];
    const float a1 = adjr[1][j0 + jj];
    {
      f4 e = hi0 * hjv;
      e.x = fmaxf(e.x, 0.2f * e.x) * a0;
      e.y = fmaxf(e.y, 0.2f * e.y) * a0;
      e.z = fmaxf(e.z, 0.2f * e.z) * a0;
      e.w = fmaxf(e.w, 0.2f * e.w) * a0;
      f4 ex;
      ex.x = __expf(e.x); ex.y = __expf(e.y);
      ex.z = __expf(e.z); ex.w = __expf(e.w);
      float sm = (ex.x + ex.y) + (ex.z + ex.w);
      sm += __shfl_xor(sm, 1); sm += __shfl_xor(sm, 2); sm += __shfl_xor(sm, 4);
      f4 a = ex * __builtin_amdgcn_rcpf(sm);
      acc0 += a;
      *(f4*)(att + ob0 + (size_t)jj * jstride) = a;
    }
    {
      f4 e = hi1 * hjv;
      e.x = fmaxf(e.x, 0.2f * e.x) * a1;
      e.y = fmaxf(e.y, 0.2f * e.y) * a1;
      e.z = fmaxf(e.z, 0.2f * e.z) * a1;
      e.w = fmaxf(e.w, 0.2f * e.w) * a1;
      f4 ex;
      ex.x = __expf(e.x); ex.y = __expf(e.y);
      ex.z = __expf(e.z); ex.w = __expf(e.w);
      float sm = (ex.x + ex.y) + (ex.z + ex.w);
      sm += __shfl_xor(sm, 1); sm += __shfl_xor(sm, 2); sm += __shfl_xor(sm, 4);
      f4 a = ex * __builtin_amdgcn_rcpf(sm);
      acc1 += a;
      *(f4*)(att + ob1 + (size_t)jj * jstride) = a;
    }
  }

  red[0][jsub][p][c4] = acc0;
  red[1][jsub][p][c4] = acc1;
  __syncthreads();

  if (jsub == 0) {
    f4 s0 = (red[0][0][p][c4] + red[0][1][p][c4]) +
            (red[0][2][p][c4] + red[0][3][p][c4]);
    f4 s1 = (red[1][0][p][c4] + red[1][1][p][c4]) +
            (red[1][2][p][c4] + red[1][3][p][c4]);
    f4 v0 = s0 * hf0;
    f4 v1 = s1 * hf1;
    v0.x = v0.x >= 0.f ? v0.x : expm1f(v0.x);
    v0.y = v0.y >= 0.f ? v0.y : expm1f(v0.y);
    v0.z = v0.z >= 0.f ? v0.z : expm1f(v0.z);
    v0.w = v0.w >= 0.f ? v0.w : expm1f(v0.w);
    v1.x = v1.x >= 0.f ? v1.x : expm1f(v1.x);
    v1.y = v1.y >= 0.f ? v1.y : expm1f(v1.y);
    v1.z = v1.z >= 0.f ? v1.z : expm1f(v1.z);
    v1.w = v1.w >= 0.f ? v1.w : expm1f(v1.w);
    *(f4*)(hprime + ((size_t)((b * Nq + i0) * Tq + t)) * COUT + c0) = v0;
    *(f4*)(hprime + ((size_t)((b * Nq + i0 + 1) * Tq + t)) * COUT + c0) = v1;
  }
}

extern "C" void kernel_launch(void* const* d_in, const int* in_sizes, int n_in,
                              void* d_out, int out_size, void* d_ws, size_t ws_size,
                              hipStream_t stream) {
  (void)in_sizes; (void)n_in; (void)out_size; (void)d_ws; (void)ws_size;
  const float* x   = (const float*)d_in[0];
  const float* adj = (const float*)d_in[1];
  const float* W   = (const float*)d_in[2];

  float* att = (float*)d_out;
  float* hp  = (float*)d_out + ATT_SIZE;

  // (b, ig, s) = 2*32*4 = 256 blocks, one per CU
  hipLaunchKernelGGL(gat_fused_kernel, dim3(Bq * 32 * NPq), dim3(768), 0, stream,
                     x, adj, W, att, hp);
}

// Round 11
// 30.902 us; speedup vs baseline: 1.8400x; 1.4278x over previous
//
#include <hip/hip_runtime.h>
#include <math.h>

#define Bq 2
#define Tq 96
#define Nq 64
#define CIN 16
#define COUT 32
#define PATCH 24
#define NPq 4
#define ATT_SIZE (Bq * Nq * Nq * Tq * COUT)   // 25165824

typedef float f4 __attribute__((ext_vector_type(4)));

// ---------------------------------------------------------------------------
// Single fused kernel. Block = (b, s, i-pair): 256 blocks x 768 threads.
// Identical to round 10 EXCEPT the main loop is now FULLY unrolled: round 10's
// "#pragma unroll 4" made hj[jj] runtime-indexed -> hj spilled to scratch
// (VGPR_Count 76, VALUBusy 0.27%, +50MB spill writes). Full unroll keeps all
// indices compile-time-constant so hj[16]+Wr[16] live in registers (cap 170).
// ---------------------------------------------------------------------------
__global__ __launch_bounds__(768, 3) void gat_fused_kernel(
    const float* __restrict__ x, const float* __restrict__ adj,
    const float* __restrict__ W,
    float* __restrict__ att, float* __restrict__ hprime) {
  const int bi = blockIdx.x;
  const int s  = bi & 3;
  const int ig = (bi >> 2) & 31;
  const int b  = bi >> 7;
  const int i0 = ig * 2;
  const int tid  = threadIdx.x;
  const int c4   = tid & 7;            // f4-quad index, c0 = c4*4
  const int p    = (tid >> 3) % PATCH; // 0..23
  const int jsub = tid / 192;          // 0..3
  const int j0   = jsub * 16;
  const int t    = p * NPq + s;

  __shared__ float adjr[2][Nq];
  __shared__ f4 red[2][4][PATCH][8];   // [i][jsub][p][c4] = 24 KB

  if (tid < 2 * Nq)
    adjr[tid >> 6][tid & 63] = adj[(i0 + (tid >> 6)) * Nq + (tid & 63)];
  __syncthreads();

  const f4* x4 = (const f4*)x;   // x row (16 f) = 4 f4
  const f4* W4 = (const f4*)W;   // W row k (32 f) = 8 f4

  // W column-slice: W[k][c0..c0+3] for k=0..15
  f4 Wr[16];
#pragma unroll
  for (int k = 0; k < 16; ++k) Wr[k] = W4[k * 8 + c4];

  // row-dot: h[row][c0..c0+3] = sum_k x[row][k] * W[k][c0..c0+3]
  auto rowdot = [&](int row) -> f4 {
    const f4 x0 = x4[row * 4 + 0], x1 = x4[row * 4 + 1];
    const f4 x2 = x4[row * 4 + 2], x3 = x4[row * 4 + 3];
    f4 a = x0.x * Wr[0];
    a += x0.y * Wr[1];  a += x0.z * Wr[2];  a += x0.w * Wr[3];
    a += x1.x * Wr[4];  a += x1.y * Wr[5];  a += x1.z * Wr[6];  a += x1.w * Wr[7];
    a += x2.x * Wr[8];  a += x2.y * Wr[9];  a += x2.z * Wr[10]; a += x2.w * Wr[11];
    a += x3.x * Wr[12]; a += x3.y * Wr[13]; a += x3.z * Wr[14]; a += x3.w * Wr[15];
    return a;
  };

  const int rbase = (b * NPq + s) * Nq;        // + n -> *PATCH + p
  const int s2 = t / PATCH, p2 = t % PATCH;    // h_flat row split

  const f4 hi0 = rowdot((rbase + i0) * PATCH + p);
  const f4 hi1 = rowdot((rbase + i0 + 1) * PATCH + p);
  const f4 hf0 = rowdot(((b * NPq + s2) * Nq + i0) * PATCH + p2);
  const f4 hf1 = rowdot(((b * NPq + s2) * Nq + i0 + 1) * PATCH + p2);

  f4 hj[16];
#pragma unroll
  for (int jj = 0; jj < 16; ++jj)
    hj[jj] = rowdot((rbase + j0 + jj) * PATCH + p);
  // Wr dead from here.

  f4 acc0 = {0.f, 0.f, 0.f, 0.f};
  f4 acc1 = {0.f, 0.f, 0.f, 0.f};
  const int c0 = c4 * 4;
  // att flat: (((b*N+i)*N+j)*T + t)*COUT + c
  size_t ob0 = ((size_t)((b * Nq + i0) * Nq + j0) * Tq + t) * COUT + c0;
  size_t ob1 = ob0 + (size_t)Nq * Tq * COUT;
  const size_t jstride = (size_t)Tq * COUT;   // 3072

#pragma unroll
  for (int jj = 0; jj < 16; ++jj) {
    const f4 hjv = hj[jj];
    const float a0 = adjr[0][j0 + jj];
    const float a1 = adjr[1][j0 + jj];
    {
      f4 e = hi0 * hjv;
      e.x = fmaxf(e.x, 0.2f * e.x) * a0;
      e.y = fmaxf(e.y, 0.2f * e.y) * a0;
      e.z = fmaxf(e.z, 0.2f * e.z) * a0;
      e.w = fmaxf(e.w, 0.2f * e.w) * a0;
      f4 ex;
      ex.x = __expf(e.x); ex.y = __expf(e.y);
      ex.z = __expf(e.z); ex.w = __expf(e.w);
      float sm = (ex.x + ex.y) + (ex.z + ex.w);
      sm += __shfl_xor(sm, 1); sm += __shfl_xor(sm, 2); sm += __shfl_xor(sm, 4);
      f4 a = ex * __builtin_amdgcn_rcpf(sm);
      acc0 += a;
      *(f4*)(att + ob0 + (size_t)jj * jstride) = a;
    }
    {
      f4 e = hi1 * hjv;
      e.x = fmaxf(e.x, 0.2f * e.x) * a1;
      e.y = fmaxf(e.y, 0.2f * e.y) * a1;
      e.z = fmaxf(e.z, 0.2f * e.z) * a1;
      e.w = fmaxf(e.w, 0.2f * e.w) * a1;
      f4 ex;
      ex.x = __expf(e.x); ex.y = __expf(e.y);
      ex.z = __expf(e.z); ex.w = __expf(e.w);
      float sm = (ex.x + ex.y) + (ex.z + ex.w);
      sm += __shfl_xor(sm, 1); sm += __shfl_xor(sm, 2); sm += __shfl_xor(sm, 4);
      f4 a = ex * __builtin_amdgcn_rcpf(sm);
      acc1 += a;
      *(f4*)(att + ob1 + (size_t)jj * jstride) = a;
    }
  }

  red[0][jsub][p][c4] = acc0;
  red[1][jsub][p][c4] = acc1;
  __syncthreads();

  if (jsub == 0) {
    f4 s0 = (red[0][0][p][c4] + red[0][1][p][c4]) +
            (red[0][2][p][c4] + red[0][3][p][c4]);
    f4 s1 = (red[1][0][p][c4] + red[1][1][p][c4]) +
            (red[1][2][p][c4] + red[1][3][p][c4]);
    f4 v0 = s0 * hf0;
    f4 v1 = s1 * hf1;
    v0.x = v0.x >= 0.f ? v0.x : expm1f(v0.x);
    v0.y = v0.y >= 0.f ? v0.y : expm1f(v0.y);
    v0.z = v0.z >= 0.f ? v0.z : expm1f(v0.z);
    v0.w = v0.w >= 0.f ? v0.w : expm1f(v0.w);
    v1.x = v1.x >= 0.f ? v1.x : expm1f(v1.x);
    v1.y = v1.y >= 0.f ? v1.y : expm1f(v1.y);
    v1.z = v1.z >= 0.f ? v1.z : expm1f(v1.z);
    v1.w = v1.w >= 0.f ? v1.w : expm1f(v1.w);
    *(f4*)(hprime + ((size_t)((b * Nq + i0) * Tq + t)) * COUT + c0) = v0;
    *(f4*)(hprime + ((size_t)((b * Nq + i0 + 1) * Tq + t)) * COUT + c0) = v1;
  }
}

extern "C" void kernel_launch(void* const* d_in, const int* in_sizes, int n_in,
                              void* d_out, int out_size, void* d_ws, size_t ws_size,
                              hipStream_t stream) {
  (void)in_sizes; (void)n_in; (void)out_size; (void)d_ws; (void)ws_size;
  const float* x   = (const float*)d_in[0];
  const float* adj = (const float*)d_in[1];
  const float* W   = (const float*)d_in[2];

  float* att = (float*)d_out;
  float* hp  = (float*)d_out + ATT_SIZE;

  // (b, ig, s) = 2*32*4 = 256 blocks, one per CU
  hipLaunchKernelGGL(gat_fused_kernel, dim3(Bq * 32 * NPq), dim3(768), 0, stream,
                     x, adj, W, att, hp);
}

// Round 12
// 29.658 us; speedup vs baseline: 1.9171x; 1.0419x over previous
//
#include <hip/hip_runtime.h>
#include <math.h>

#define Bq 2
#define Tq 96
#define Nq 64
#define CIN 16
#define COUT 32
#define PATCH 24
#define NPq 4
#define ATT_SIZE (Bq * Nq * Nq * Tq * COUT)   // 25165824
#define H_ROWS (Bq * NPq * Nq * PATCH)        // 12288

typedef float f4 __attribute__((ext_vector_type(4)));

// ---------------------------------------------------------------------------
// Kernel 1: h = x_flat(12288,16) @ W(16,32).
// ---------------------------------------------------------------------------
__global__ __launch_bounds__(256) void h_gemm_kernel(
    const float* __restrict__ x, const float* __restrict__ W,
    float* __restrict__ h) {
    __shared__ float Wl[CIN * COUT];
    __shared__ float xs[8 * CIN];
    int tid = threadIdx.x;
    Wl[tid]       = W[tid];
    Wl[tid + 256] = W[tid + 256];
    if (tid < 8 * CIN) xs[tid] = x[blockIdx.x * (8 * CIN) + tid];
    __syncthreads();
    int rl = tid >> 5;
    int c  = tid & 31;
    float acc = 0.f;
#pragma unroll
    for (int k = 0; k < CIN; ++k)
        acc += xs[rl * CIN + k] * Wl[k * COUT + c];
    h[blockIdx.x * 256 + tid] = acc;
}

// ---------------------------------------------------------------------------
// Kernel 2 (fused): round-6 champion structure, ONE CHANGE: bijective
// XCD-chunked blockIdx swizzle (T1). Default round-robin dispatch puts the
// 4 s-sibling blocks (which jointly cover each contiguous output region) on
// 4 different XCDs -> every XCD L2 write-back stream is scattered over the
// whole 101 MB. Remap g -> orig = (g&7)*64 + (g>>3): XCD c owns a contiguous
// 12.6 MB att region (fixed b, 16 consecutive i, all s) -> dense per-L2
// write-back, DRAM row-buffer friendly (fill-kernel-like).
// ---------------------------------------------------------------------------
__global__ __launch_bounds__(768) void att_fused_kernel(
    const float* __restrict__ h, const float* __restrict__ adj,
    float* __restrict__ att, float* __restrict__ hprime) {
    const int g  = blockIdx.x;
    const int bi = (g & 7) * 64 + (g >> 3);   // bijective: 512 = 8 XCD * 64
    const int s  = bi & 3;
    const int i  = (bi >> 2) & 63;
    const int b  = bi >> 8;
    const int tid  = threadIdx.x;
    const int c0   = (tid & 7) * 4;      // channel quad base
    const int p    = (tid >> 3) % PATCH; // 0..23
    const int jsub = tid / 192;          // 0..3
    const int j0   = jsub * 16;

    __shared__ float adjrow[Nq];
    __shared__ f4 red[768];
    if (tid < Nq) adjrow[tid] = adj[i * Nq + tid];
    __syncthreads();

    const float* hb = h + (size_t)((b * NPq + s) * Nq) * (PATCH * COUT);
    const f4 hi = *(const f4*)(hb + (i * PATCH + p) * COUT + c0);

    f4 acc = {0.f, 0.f, 0.f, 0.f};
    const int t = p * NPq + s;
    // att flat index: (((b*N+i)*N+j)*T + t)*COUT + c
    size_t outbase = ((size_t)((b * Nq + i) * Nq + j0) * Tq + t) * COUT + c0;
    const size_t jstride = (size_t)Tq * COUT;   // 3072

#pragma unroll 4
    for (int jj = 0; jj < 16; ++jj) {
        const f4 hj = *(const f4*)(hb + ((j0 + jj) * PATCH + p) * COUT + c0);
        const float aj = adjrow[j0 + jj];

        f4 e = hi * hj;
        e.x = fmaxf(e.x, 0.2f * e.x) * aj;   // LeakyReLU(0.2) then *adj
        e.y = fmaxf(e.y, 0.2f * e.y) * aj;
        e.z = fmaxf(e.z, 0.2f * e.z) * aj;
        e.w = fmaxf(e.w, 0.2f * e.w) * aj;

        f4 ex;
        ex.x = __expf(e.x); ex.y = __expf(e.y);
        ex.z = __expf(e.z); ex.w = __expf(e.w);
        float sm = (ex.x + ex.y) + (ex.z + ex.w);
#pragma unroll
        for (int d = 1; d < 8; d <<= 1) sm += __shfl_xor(sm, d);
        const float inv = __builtin_amdgcn_rcpf(sm);
        f4 a = ex * inv;
        acc += a;
        *(f4*)(att + outbase + (size_t)jj * jstride) = a;
    }

    red[tid] = acc;
    __syncthreads();

    if (jsub == 0) {
        const f4 a0 = red[tid];
        const f4 a1 = red[tid + 192];
        const f4 a2 = red[tid + 384];
        const f4 a3 = red[tid + 576];
        f4 asum = (a0 + a1) + (a2 + a3);

        // h_flat[b,i,t,c]: t = s2*24 + p2
        const int s2 = t / PATCH;
        const int p2 = t % PATCH;
        const f4 hv = *(const f4*)(h + (size_t)((b * NPq + s2) * Nq + i) * (PATCH * COUT)
                                     + p2 * COUT + c0);
        f4 v = asum * hv;
        v.x = v.x >= 0.f ? v.x : expm1f(v.x);
        v.y = v.y >= 0.f ? v.y : expm1f(v.y);
        v.z = v.z >= 0.f ? v.z : expm1f(v.z);
        v.w = v.w >= 0.f ? v.w : expm1f(v.w);
        *(f4*)(hprime + ((size_t)((b * Nq + i) * Tq + t)) * COUT + c0) = v;
    }
}

extern "C" void kernel_launch(void* const* d_in, const int* in_sizes, int n_in,
                              void* d_out, int out_size, void* d_ws, size_t ws_size,
                              hipStream_t stream) {
    (void)in_sizes; (void)n_in; (void)out_size; (void)ws_size;
    const float* x   = (const float*)d_in[0];
    const float* adj = (const float*)d_in[1];
    const float* W   = (const float*)d_in[2];

    float* h   = (float*)d_ws;              // 393216 floats = 1.57 MB
    float* att = (float*)d_out;
    float* hp  = (float*)d_out + ATT_SIZE;

    hipLaunchKernelGGL(h_gemm_kernel, dim3(H_ROWS / 8), dim3(256), 0, stream,
                       x, W, h);
    // (b, i, s) = 2*64*4 = 512 blocks, XCD-chunk-swizzled inside the kernel
    hipLaunchKernelGGL(att_fused_kernel, dim3(Bq * Nq * NPq), dim3(768), 0, stream,
                       h, adj, att, hp);
}